// Round 13
// baseline (125.106 us; speedup 1.0000x reference)
//
#include <hip/hip_runtime.h>

// EmbedDNF: B=128, IN_F=256, HID=512, OUT=128, E=8 (fp32, e innermost)
//
// impl = 1 - w*(1-xnor) = A + x*Bv ; A = 1 - w*s ; Bv = 2*w*s - w
// H[b,h,e]   = prod_i (A[i,h,e] + x[b,i,e]*Bv[i,h,e])
// out[b,o,e] = 1 - prod_h (1 - dw[h,o,e]*H[b,h,e])
//
// Laws (R4-R12): (1) acc <= 32 VGPR, inner loop = <=2 VMEM streams +
// immediate-offset LDS broadcasts (4 spill regressions); (2) 1024-thr blocks
// need __launch_bounds__(1024,1) for VGPR cap 128 (R5 spilled at (1024,4));
// (3) no device-scope fences (R9); (4) keep >=16 waves/CU (R11);
// (5) R12==R7 => kernels are sub-dominant; fixed node cost ~8-10us => fewer
// kernels + no partial-array round-trips. This round: 2 in-block-complete
// kernels (k1 full-i -> H direct; k2 full-h, LDS-free inner loop -> out).
//
// ws: H [512][128][8] fp32 @ 0 (2 MB, h-major)

#define LD4(p) (*(const float4*)(p))

static __device__ __forceinline__ float4 f4mul(float4 a, float4 b) {
    return make_float4(a.x*b.x, a.y*b.y, a.z*b.z, a.w*b.w);
}
static __device__ __forceinline__ float4 f4fma(float4 a, float4 b, float4 c) {
    return make_float4(fmaf(a.x,b.x,c.x), fmaf(a.y,b.y,c.y),
                       fmaf(a.z,b.z,c.z), fmaf(a.w,b.w,c.w));
}
static __device__ __forceinline__ float4 f4nfma1(float4 d, float4 h) {  // 1-d*h
    return make_float4(fmaf(-d.x,h.x,1.0f), fmaf(-d.y,h.y,1.0f),
                       fmaf(-d.z,h.z,1.0f), fmaf(-d.w,h.w,1.0f));
}

// ---------------------------------------------------------------------------
// Kernel 1: full-i stage1 -> H. Grid 256 = hg16 (32 h, low bits: XCD L2
// slicing) x bg16 (8 b). Block 1024 = 16 waves = 16 i-chunks of 16.
// Lane = eh2 x hl32; thread tile 8b x 1h x 4e (acc = 32 VGPR, R7-proven).
// Prologue: x-tile [8 b][256 i][8 e] (64 KB) -> LDS, coalesced.
// Wave inner loop = R7 VERBATIM: 16 steps x (2 contiguous 1 KB VMEM (w,s) +
// 8 immediate-offset ds_read_b128 + ~76 VALU).
// Combine: 16 wave-partials x [8b][32h][8e]; 2 phases of 4 b in the reused
// 64 KB x-region; H written directly (no P1).
// ---------------------------------------------------------------------------
__global__ __launch_bounds__(1024, 1) void k_stage1(
    const float* __restrict__ in,   // [128][256][8]
    const float* __restrict__ cw,   // [256][512][8]
    const float* __restrict__ cs,   // [256][512][8]
    float* __restrict__ H)          // ws: [512][128][8]
{
    __shared__ float lds[16384];             // 64 KB: x-tile, then combine
    const int t    = threadIdx.x;
    const int lane = t & 63;
    const int wv   = t >> 6;                 // i-chunk 0..15
    const int eh   = lane & 1;
    const int hl   = lane >> 1;              // 0..31
    const int hg   = blockIdx.x & 15;        // low bits: XCD-sliced cw/cs
    const int bg   = blockIdx.x >> 4;
    const int b0   = bg * 8;
    const int h    = hg * 32 + hl;
    const int e0   = eh * 4;

    // stage x[b0:+8][0:256][0:8] -> lds (layout [b][i][e]), coalesced
    {
        float4* xs4 = (float4*)lds;
        #pragma unroll
        for (int k = 0; k < 4; ++k) {
            const int f4  = t + k * 1024;    // 0..4095
            const int b   = f4 >> 9;         // 512 float4 per b-row
            const int col = f4 & 511;
            xs4[f4] = LD4(in + (b0 + b) * 2048 + col * 4);
        }
    }
    __syncthreads();

    const int i0 = wv * 16;
    const float* pw = cw + i0 * 4096 + h * 8 + e0;
    const float* ps = cs + i0 * 4096 + h * 8 + e0;
    const float* xbase = lds + i0 * 8 + e0;     // + b*2048 + ii*8 (immediates)

    float4 acc[8];
    #pragma unroll
    for (int b = 0; b < 8; ++b) acc[b] = make_float4(1.f, 1.f, 1.f, 1.f);

    #pragma unroll
    for (int ii = 0; ii < 16; ++ii) {
        const float4 wvv = LD4(pw);
        const float4 sv  = LD4(ps);
        pw += 4096; ps += 4096;
        const float4 p  = f4mul(wvv, sv);
        const float4 A  = make_float4(1.f - p.x, 1.f - p.y, 1.f - p.z, 1.f - p.w);
        const float4 Bv = make_float4(fmaf(2.f, p.x, -wvv.x), fmaf(2.f, p.y, -wvv.y),
                                      fmaf(2.f, p.z, -wvv.z), fmaf(2.f, p.w, -wvv.w));
        #pragma unroll
        for (int b = 0; b < 8; ++b) {
            const float4 xv = LD4(xbase + b * 2048 + ii * 8);
            acc[b] = f4mul(acc[b], f4fma(xv, Bv, A));
        }
    }

    __syncthreads();                         // all waves done reading x-tile
    // combine 16 wave-partials, 2 phases of 4 b (each phase: 16 x 1024 floats)
    #pragma unroll
    for (int phase = 0; phase < 2; ++phase) {
        if (phase) __syncthreads();          // protect phase-0 reads
        #pragma unroll
        for (int j = 0; j < 4; ++j)
            *(float4*)&lds[wv * 1024 + j * 256 + hl * 8 + e0] = acc[phase * 4 + j];
        __syncthreads();
        {   // 1024 outs/phase, 1024 threads: idx t = j*256 + hl2*8 + e
            float m = lds[t];
            #pragma unroll
            for (int c = 1; c < 16; ++c) m *= lds[c * 1024 + t];
            const int j   = t >> 8;
            const int hl2 = (t >> 3) & 31;
            const int e   = t & 7;
            H[(hg * 32 + hl2) * 1024 + (b0 + phase * 4 + j) * 8 + e] = m;
        }
    }
}

// ---------------------------------------------------------------------------
// Kernel 2: full-h stage2 -> out. Grid 512 = og32 (4 o, low bits: XCD dw
// slicing) x bg16 (8 b). Block 1024 = 16 waves = 16 h-chunks of 32.
// Lane = eh2 x ol4 x bl8; thread tile 1b x 1o x 4e (acc = 4 VGPR).
// LDS-FREE inner loop: 32 steps x (dw load 128 B/wave + H load 256 B
// contiguous/wave + 1 f4-VALU). 32 waves/CU. Combine: 16 KB LDS, one pass.
// ---------------------------------------------------------------------------
__global__ __launch_bounds__(1024, 2) void k_stage2(
    const float* __restrict__ dw,   // [512][128][8]
    const float* __restrict__ H,    // ws: [512][128][8]
    float* __restrict__ out)        // [128][128][8]
{
    __shared__ float lds[4096];              // 16 KB combine buffer
    const int t    = threadIdx.x;
    const int lane = t & 63;
    const int wv   = t >> 6;                 // h-chunk 0..15 (32 h each)
    const int eh   = lane & 1;
    const int ol   = (lane >> 1) & 3;
    const int bl   = lane >> 3;              // 0..7
    const int og   = blockIdx.x & 31;        // low bits: XCD-sliced dw
    const int bg   = blockIdx.x >> 5;
    const int b0   = bg * 8;
    const int o0   = og * 4;
    const int e0   = eh * 4;

    const float* ph = H  + (wv * 32) * 1024 + (b0 + bl) * 8 + e0;
    const float* pd = dw + (wv * 32) * 1024 + (o0 + ol) * 8 + e0;

    float4 acc = make_float4(1.f, 1.f, 1.f, 1.f);
    #pragma unroll
    for (int ii = 0; ii < 32; ++ii) {
        const float4 dv = LD4(pd);
        const float4 hv = LD4(ph);
        pd += 1024; ph += 1024;
        acc = f4mul(acc, f4nfma1(dv, hv));
    }

    // combine 16 wave-partials: lds[wv][bl*32 + ol*8 + e]
    *(float4*)&lds[wv * 256 + bl * 32 + ol * 8 + e0] = acc;
    __syncthreads();

    if (t < 256) {                           // 256 outputs, idx t = bl*32+ol*8+e
        float m = lds[t];
        #pragma unroll
        for (int c = 1; c < 16; ++c) m *= lds[c * 256 + t];
        const int blo = t >> 5;
        const int olo = (t >> 3) & 3;
        const int e   = t & 7;
        out[(b0 + blo) * 1024 + (o0 + olo) * 8 + e] = 1.0f - m;
    }
}

extern "C" void kernel_launch(void* const* d_in, const int* in_sizes, int n_in,
                              void* d_out, int out_size, void* d_ws, size_t ws_size,
                              hipStream_t stream)
{
    const float* in = (const float*)d_in[0];   // [128][256][8]
    const float* cw = (const float*)d_in[1];   // [256][512][8]
    const float* cs = (const float*)d_in[2];   // [256][512][8]
    const float* dw = (const float*)d_in[3];   // [512][128][8]
    float* outp = (float*)d_out;               // [128][128][8]
    float* H    = (float*)d_ws;                // 2 MB used

    k_stage1<<<256, 1024, 0, stream>>>(in, cw, cs, H);
    k_stage2<<<512, 1024, 0, stream>>>(dw, H, outp);
}

// Round 14
// 97.273 us; speedup vs baseline: 1.2861x; 1.2861x over previous
//
#include <hip/hip_runtime.h>

// EmbedDNF: B=128, IN_F=256, HID=512, OUT=128, E=8 (fp32, e innermost)
//
// impl = 1 - w*(1-xnor) = A + x*Bv ; A = 1 - w*s ; Bv = 2*w*s - w
// H[b,h,e]   = prod_i (A[i,h,e] + x[b,i,e]*Bv[i,h,e])
// out[b,o,e] = 1 - prod_h (1 - dw[h,o,e]*H[b,h,e])
//
// FINAL (R14 = R12 revert, best proven: 97.1 us).
// Laws learned (R4-R13):
// (1) acc <= 32 VGPR; inner loop = <=2 VMEM streams + immediate-offset LDS
//     broadcasts; NO restructuring (5 spill regressions: R5/R6/R8/R10/R13).
// (2) broadcast operands (x, H) live in LDS, staged coalesced.
// (3) no device-scope fences/atomics in hot path (R9: +60 us).
// (4) keep >= 4 blocks/CU resident (R10/R11 starvation).
// (5) 1024-thread blocks always get VGPR cap 64 -> spill (R5, R13).
// (6) R7 == R12 despite 2x occupancy: kernel time is sub-dominant; the
//     residual is harness fill (42 us, 256 MiB poison) + reset/graph cost.
//
// ws: P1 [8][512][128][8] fp32 @ 0        (16 MB)  stage1 i-split partials
//     P2 [16][128][128][8] fp32 @ 4194304 (8 MB)   stage2 h-split partials

#define LD4(p) (*(const float4*)(p))

static __device__ __forceinline__ float4 f4mul(float4 a, float4 b) {
    return make_float4(a.x*b.x, a.y*b.y, a.z*b.z, a.w*b.w);
}
static __device__ __forceinline__ float4 f4fma(float4 a, float4 b, float4 c) {
    return make_float4(fmaf(a.x,b.x,c.x), fmaf(a.y,b.y,c.y),
                       fmaf(a.z,b.z,c.z), fmaf(a.w,b.w,c.w));
}
static __device__ __forceinline__ float4 f4nfma1(float4 d, float4 h) {  // 1-d*h
    return make_float4(fmaf(-d.x,h.x,1.0f), fmaf(-d.y,h.y,1.0f),
                       fmaf(-d.z,h.z,1.0f), fmaf(-d.w,h.w,1.0f));
}

// ---------------------------------------------------------------------------
// Stage 1. Grid 2048 = hg16 (32 h, low bits: XCD L2 slicing) x bg16 (8 b) x
// ks8 (32 i). Block 256 = 4 waves = 4 i-subchunks of 8. Lane = eh2 x hl32;
// thread tile 8b x 1h x 4e (acc = 32 VGPR, R7-proven).
// Prologue: x-tile [8 b][32 i][8 e] (8 KB) -> LDS, coalesced.
// Step: 2 streaming VMEM (w,s contiguous 1 KB wave-loads) + 8 immediate-
// offset ds_read_b128 broadcasts + ~60 VALU.  8 steps.
// kc-partials combined in 2 phases of 4 b (16 KB LDS total, reused buffer).
// ---------------------------------------------------------------------------
__global__ __launch_bounds__(256, 4) void k_stage1(
    const float* __restrict__ in,   // [128][256][8]
    const float* __restrict__ cw,   // [256][512][8]
    const float* __restrict__ cs,   // [256][512][8]
    float* __restrict__ P1)         // ws: [8][512][128][8]
{
    __shared__ float lds[4096];              // 16 KB: x-tile [0,2048) then combine
    const int t    = threadIdx.x;
    const int lane = t & 63;
    const int kc   = t >> 6;                 // 0..3
    const int eh   = lane & 1;
    const int hl   = lane >> 1;              // 0..31
    const int hg   = blockIdx.x & 15;
    const int bg   = (blockIdx.x >> 4) & 15;
    const int ks   = blockIdx.x >> 8;        // 0..7
    const int b0   = bg * 8;
    const int h    = hg * 32 + hl;
    const int e0   = eh * 4;

    // stage x[b0:+8][ks*32:+32][0:8] -> lds (layout [b][il][e]), coalesced
    {
        float4* xs4 = (float4*)lds;
        #pragma unroll
        for (int k = 0; k < 2; ++k) {
            const int f4  = t + k * 256;     // 0..511
            const int b   = f4 >> 6;
            const int col = f4 & 63;         // float4 within 256-float row
            xs4[f4] = LD4(in + (b0 + b) * 2048 + ks * 256 + col * 4);
        }
    }
    __syncthreads();

    const int i0 = ks * 32 + kc * 8;
    const float* pw = cw + i0 * 4096 + h * 8 + e0;
    const float* ps = cs + i0 * 4096 + h * 8 + e0;
    const float* xbase = lds + kc * 64 + e0;    // + b*256 + ii*8 (immediates)

    float4 acc[8];
    #pragma unroll
    for (int b = 0; b < 8; ++b) acc[b] = make_float4(1.f, 1.f, 1.f, 1.f);

    #pragma unroll
    for (int ii = 0; ii < 8; ++ii) {
        const float4 wv = LD4(pw);
        const float4 sv = LD4(ps);
        pw += 4096; ps += 4096;
        const float4 p  = f4mul(wv, sv);
        const float4 A  = make_float4(1.f - p.x, 1.f - p.y, 1.f - p.z, 1.f - p.w);
        const float4 Bv = make_float4(fmaf(2.f, p.x, -wv.x), fmaf(2.f, p.y, -wv.y),
                                      fmaf(2.f, p.z, -wv.z), fmaf(2.f, p.w, -wv.w));
        #pragma unroll
        for (int b = 0; b < 8; ++b) {
            const float4 xv = LD4(xbase + b * 256 + ii * 8);
            acc[b] = f4mul(acc[b], f4fma(xv, Bv, A));
        }
    }

    __syncthreads();                         // x-tile dead; reuse lds
    // 2 phases of 4 b: partial[kc][j4][hl32][e8] = 1024 floats per kc
    #pragma unroll
    for (int phase = 0; phase < 2; ++phase) {
        if (phase) __syncthreads();          // protect phase-0 reads
        #pragma unroll
        for (int j = 0; j < 4; ++j)
            *(float4*)&lds[kc * 1024 + j * 256 + hl * 8 + e0] = acc[phase * 4 + j];
        __syncthreads();
        {   // combine 4 kc; thread t -> one float4 of the 1024-float tile
            const int o4 = t * 4;            // j*256 + hl2*8 + eq*4
            float4 m = LD4(&lds[o4]);
            #pragma unroll
            for (int c = 1; c < 4; ++c) m = f4mul(m, LD4(&lds[c * 1024 + o4]));
            const int j   = o4 >> 8;
            const int hl2 = (o4 >> 3) & 31;
            const int eq  = o4 & 7;          // 0 or 4
            *(float4*)(P1 + ks * 524288 + (hg * 32 + hl2) * 1024
                          + (b0 + phase * 4 + j) * 8 + eq) = m;
        }
    }
}

// ---------------------------------------------------------------------------
// Stage 2. Grid 1024 = og4 (32 o, low bits: dw XCD slicing) x bg16 (8 b) x
// ks16 (32 h). Block 256 = 4 waves = 4 h-subchunks of 8. Lane = eh2 x ol32;
// thread tile 8b x 1o x 4e (acc = 32 VGPR, R7-proven).
// Prologue: H-tile [32 h][8 b][8 e] (8 KB) = product of 8 P1 copies -> LDS.
// Step: 1 streaming VMEM (dw contiguous 1 KB wave-load) + 8 immediate-offset
// ds_read_b128 broadcasts + 64 VALU.  8 steps.
// kc-partials combined in 2 phases of 4 b; ks-partials -> P2.
// ---------------------------------------------------------------------------
__global__ __launch_bounds__(256, 4) void k_stage2(
    const float* __restrict__ dw,   // [512][128][8]
    const float* __restrict__ P1,   // ws: [8][512][128][8]
    float* __restrict__ P2)         // ws: [16][128][128][8]
{
    __shared__ float lds[4096];              // 16 KB: H-tile [0,2048) then combine
    const int t    = threadIdx.x;
    const int lane = t & 63;
    const int kc   = t >> 6;                 // 0..3
    const int eh   = lane & 1;
    const int ol   = lane >> 1;              // 0..31
    const int og   = blockIdx.x & 3;
    const int bg   = (blockIdx.x >> 2) & 15;
    const int ks   = blockIdx.x >> 6;        // 0..15
    const int b0   = bg * 8;
    const int o    = og * 32 + ol;
    const int e0   = eh * 4;
    const int h0   = ks * 32;

    // H-tile: product of the 8 i-split partials, layout [hl][b][e]
    {
        float4* ht4 = (float4*)lds;
        #pragma unroll
        for (int k = 0; k < 2; ++k) {
            const int f4  = t + k * 256;     // 0..511
            const int hl  = f4 >> 4;
            const int rem = f4 & 15;         // b*2 + eq
            const float* q = P1 + (h0 + hl) * 1024 + b0 * 8 + rem * 4;
            float4 m = LD4(q);
            #pragma unroll
            for (int c = 1; c < 8; ++c) m = f4mul(m, LD4(q + c * 524288));
            ht4[f4] = m;
        }
    }
    __syncthreads();

    const float* pd = dw + (h0 + kc * 8) * 1024 + o * 8 + e0;
    const float* hbase = lds + kc * 512 + e0;   // + ii*64 + b*8 (immediates)

    float4 acc[8];
    #pragma unroll
    for (int b = 0; b < 8; ++b) acc[b] = make_float4(1.f, 1.f, 1.f, 1.f);

    #pragma unroll
    for (int ii = 0; ii < 8; ++ii) {
        const float4 dv = LD4(pd);
        pd += 1024;
        #pragma unroll
        for (int b = 0; b < 8; ++b) {
            const float4 hv = LD4(hbase + ii * 64 + b * 8);
            acc[b] = f4mul(acc[b], f4nfma1(dv, hv));
        }
    }

    __syncthreads();                         // H-tile dead; reuse lds
    // 2 phases of 4 b: partial[kc][j4][ol32][e8] = 1024 floats per kc
    #pragma unroll
    for (int phase = 0; phase < 2; ++phase) {
        if (phase) __syncthreads();
        #pragma unroll
        for (int j = 0; j < 4; ++j)
            *(float4*)&lds[kc * 1024 + j * 256 + ol * 8 + e0] = acc[phase * 4 + j];
        __syncthreads();
        {
            const int o4 = t * 4;            // j*256 + ol2*8 + eq*4
            float4 m = LD4(&lds[o4]);
            #pragma unroll
            for (int c = 1; c < 4; ++c) m = f4mul(m, LD4(&lds[c * 1024 + o4]));
            const int j   = o4 >> 8;
            const int ol2 = (o4 >> 3) & 31;
            const int eq  = o4 & 7;
            *(float4*)(P2 + ks * 131072 + (b0 + phase * 4 + j) * 1024
                          + (og * 32 + ol2) * 8 + eq) = m;
        }
    }
}

// ---------------------------------------------------------------------------
// Final: out = 1 - prod over the 16 h-split partials. 8 MB read, 0.5 MB write.
// ---------------------------------------------------------------------------
__global__ __launch_bounds__(256, 4) void k_comb2(
    const float* __restrict__ P2,   // ws: [16][128][128][8]
    float* __restrict__ out)        // [128][128][8]
{
    const int idx4 = blockIdx.x * 256 + threadIdx.x;   // 0..32767
    float4 m = LD4(P2 + idx4 * 4);
    #pragma unroll
    for (int c = 1; c < 16; ++c)
        m = f4mul(m, LD4(P2 + c * 131072 + idx4 * 4));
    const float4 r = make_float4(1.f - m.x, 1.f - m.y, 1.f - m.z, 1.f - m.w);
    *(float4*)(out + idx4 * 4) = r;
}

extern "C" void kernel_launch(void* const* d_in, const int* in_sizes, int n_in,
                              void* d_out, int out_size, void* d_ws, size_t ws_size,
                              hipStream_t stream)
{
    const float* in = (const float*)d_in[0];   // [128][256][8]
    const float* cw = (const float*)d_in[1];   // [256][512][8]
    const float* cs = (const float*)d_in[2];   // [256][512][8]
    const float* dw = (const float*)d_in[3];   // [512][128][8]
    float* outp = (float*)d_out;               // [128][128][8]
    float* P1   = (float*)d_ws;                // 16 MB
    float* P2   = (float*)d_ws + 4194304;      // 8 MB

    k_stage1<<<2048, 256, 0, stream>>>(in, cw, cs, P1);
    k_stage2<<<1024, 256, 0, stream>>>(dw, P1, P2);
    k_comb2<<<128, 256, 0, stream>>>(P2, outp);
}